// Round 22
// baseline (138.253 us; speedup 1.0000x reference)
//
#include <hip/hip_runtime.h>
#include <math.h>

#define N_SAMP 4096
#define NS     7
#define DT_F   1e-5f
#define B0_F   80.0f
#define T2_F   1.0f
#define SW_F   1000.0f
#define TWO_PI 6.2831853071795864769f

// ws layout (floats): Vt 0..16384 | lam 16384..16512 | U 16512..32896 |
//                     wc 49280..52352 | ab(int) 52352..55424 |
//                     fidf(float2) 65664..73856 | part 73856..139392
// out (f32, 24576): ReFID [0,4096) | time [4096,8192) |
//                   Re shifted spec [8192,16384) | freq [16384,24576)

// One-sided Jacobi per sector, ONE WAVE per sector, column state in LDS
// (register versions r19-r21 were force-spilled to scratch by the compiler).
// Lockstep + in-order per-wave LDS queue => no barriers in the sweep; both
// lanes of a pair read each element's OLD value before it is overwritten.
// Stride 37 (== 5 mod 32) => 2 lanes/bank = conflict-free (G4).
__global__ __launch_bounds__(64) void k_eig(const float* __restrict__ h,
                                            float* __restrict__ Vt_full,
                                            float* __restrict__ U,
                                            float* __restrict__ lam_out) {
    const int nsz_[8]   = {1, 7, 21, 35, 35, 21, 7, 1};
    const int nbase_[8] = {0, 1, 8, 29, 64, 99, 120, 127};
    const int s    = blockIdx.x;
    const int ns   = nsz_[s];
    const int base = nbase_[s];
    const int lane = threadIdx.x;
    const int m    = ns + 1;          // even; column m-1 is zero padding
    const int nr   = ns;              // rounds in one full sweep

    __shared__ float Bl[36 * 37];     // column c at Bl[c*37 + e]
    __shared__ float hs[49];
    __shared__ int   st[36];
    __shared__ int   inv2[128];
    __shared__ float inorm_s[36];

    if (lane < 49) hs[lane] = h[lane];
    if (lane == 0) {
        int cnt = 0;
        for (int r = 0; r < 128; ++r) if (__popc(r) == s) st[cnt++] = r;
    }
    for (int t = lane; t < 36 * 37; t += 64) Bl[t] = 0.f;
    __syncthreads();
    if (lane < ns) inv2[st[lane]] = lane;

    const float SIGMA = 10000.0f;
    // build B = A_sector + SIGMA*I, column-major (A symmetric)
    for (int e2 = lane; e2 < ns * ns; e2 += 64) {
        int cidx = e2 / ns, eidx = e2 - cidx * ns;
        int r = st[eidx], c = st[cidx];
        float val = 0.f;
        if (r == c) {
            float acc = 0.f;
            for (int a = 0; a < 7; ++a) {
                float za = ((r >> (6 - a)) & 1) ? -0.5f : 0.5f;
                acc += B0_F * hs[a * 7 + a] * za;
                for (int b = a + 1; b < 7; ++b) {
                    float zb = ((r >> (6 - b)) & 1) ? -0.5f : 0.5f;
                    acc += hs[a * 7 + b] * za * zb;
                }
            }
            val = TWO_PI * acc + SIGMA;
        } else {
            int x = r ^ c;
            if (__popc(x) == 2) {
                int u = 31 - __clz(x);
                int v = __ffs(x) - 1;
                if (((r >> u) & 1) != ((r >> v) & 1))
                    val = TWO_PI * 0.5f * hs[(6 - u) * 7 + (6 - v)];
            }
        }
        Bl[cidx * 37 + eidx] = val;
    }
    __syncthreads();

    float* mycol = &Bl[lane * 37];

    for (int t = 0; t < nr; ++t) {
        // tournament partner (mutual): fixed player m-1 pairs with t
        int pj;
        if (lane >= m) pj = lane;
        else if (lane == m - 1) pj = t;
        else {
            int pos = lane - t; if (pos < 0) pos += nr;
            if (pos == 0) pj = m - 1;
            else { int pp = (2 * t - lane) % nr; if (pp < 0) pp += nr; pj = pp; }
        }
        const float* pcol = &Bl[(pj < 36 ? pj : lane) * 37];

        // pass 1: alpha = ||own||^2, gamma = own . partner (bitwise-equal on pair)
        float a0=0,a1=0,a2=0,a3=0, g0=0,g1=0,g2=0,g3=0;
        if (lane < ns) {
#pragma unroll
            for (int e = 0; e < 36; e += 4) {
                float b0=mycol[e],   c0=pcol[e];
                float b1=mycol[e+1], c1=pcol[e+1];
                float b2=mycol[e+2], c2=pcol[e+2];
                float b3=mycol[e+3], c3=pcol[e+3];
                a0+=b0*b0; g0+=b0*c0; a1+=b1*b1; g1+=b1*c1;
                a2+=b2*b2; g2+=b2*c2; a3+=b3*b3; g3+=b3*c3;
            }
        }
        float alpha = (a0 + a1) + (a2 + a3);
        float gamma = (g0 + g1) + (g2 + g3);
        float beta  = __shfl(alpha, pj);

        float cr = 1.f, sgn = 0.f;
        bool active = (lane < ns) && (pj < ns) && (pj != lane);
        if (active && fabsf(gamma) >= 1e-20f) {
            bool amin = lane < pj;
            float amn = amin ? alpha : beta;
            float amx = amin ? beta  : alpha;
            float tau = (amx - amn) / (2.f * gamma);
            float tt  = copysignf(1.f / (fabsf(tau) + sqrtf(1.f + tau * tau)), tau);
            float c   = rsqrtf(1.f + tt * tt);
            float sn  = tt * c;
            cr  = c;
            sgn = amin ? -sn : sn;   // min: c*B - sn*C ; max: c*B + sn*C
        }
        // pass 2: rotate own column in place (lockstep: reads of element e on
        // both lanes precede the write instruction for element e)
        if (lane < ns) {
#pragma unroll
            for (int e = 0; e < 36; ++e) {
                float be = mycol[e], ce = pcol[e];
                mycol[e] = cr * be + sgn * ce;
            }
        }
    }

    // eigenvalues + inverse norms
    float n0=0,n1=0,n2=0,n3=0;
    if (lane < ns) {
#pragma unroll
        for (int e = 0; e < 36; e += 4) {
            float b0=mycol[e], b1=mycol[e+1], b2=mycol[e+2], b3=mycol[e+3];
            n0+=b0*b0; n1+=b1*b1; n2+=b2*b2; n3+=b3*b3;
        }
        float nrm = sqrtf((n0 + n1) + (n2 + n3));
        lam_out[base + lane] = nrm - SIGMA;
        inorm_s[lane] = 1.f / nrm;
    }
    __syncthreads();
    // coalesced writeback of Vt rows + fused U rows
    for (int a = 0; a < ns; ++a) {
        float io = inorm_s[a];
        for (int rr = lane; rr < 128; rr += 64) {
            int pc = __popc(rr);
            float v = (pc == s) ? Bl[a * 37 + inv2[rr]] * io : 0.f;
            Vt_full[(base + a) * 128 + rr] = v;
            float uval = 0.f;
            if (pc == s - 1) {
#pragma unroll
                for (int p = 0; p < 7; ++p)
                    if (!((rr >> p) & 1)) uval += Bl[a * 37 + inv2[rr + (1 << p)]];
                uval *= io;
            }
            U[(base + a) * 128 + rr] = uval;
        }
    }
}

// Compact W: only sector-pair (s -> s+1) entries are nonzero; 3003 entries,
// padded to 3072. wc[e] = 0.5*(Vt[a]·U[b])^2, ab[e] = (a<<7)|b.
__global__ __launch_bounds__(128) void k_mwc(const float* __restrict__ Vt,
                                             const float* __restrict__ U,
                                             float* __restrict__ wc,
                                             int* __restrict__ ab) {
    const int n2_[7]   = {7, 21, 35, 35, 21, 7, 1};
    const int offs_[7] = {0, 7, 154, 889, 2114, 2849, 2996};
    const int nb1_[7]  = {0, 1, 8, 29, 64, 99, 120};
    const int nb2_[7]  = {1, 8, 29, 64, 99, 120, 127};
    int e = blockIdx.x * 128 + threadIdx.x;
    if (e >= 3072) return;
    if (e >= 3003) { wc[e] = 0.f; ab[e] = 0; return; }
    int s = 0;
#pragma unroll
    for (int t = 1; t < 7; ++t) if (e >= offs_[t]) s = t;
    int loc = e - offs_[s];
    int i = loc / n2_[s];
    int j = loc - i * n2_[s];
    int a = nb1_[s] + i, b = nb2_[s] + j;
    float acc = 0.f;
    for (int r = 0; r < 128; ++r) acc += Vt[a * 128 + r] * U[b * 128 + r];
    wc[e] = 0.5f * acc * acc;
    ab[e] = (a << 7) | b;
}

// 8 samples per block via phasor recurrence over the 3072 compact entries
__global__ __launch_bounds__(256) void k_fid(const float* __restrict__ wc,
                                             const int* __restrict__ ab,
                                             const float* __restrict__ lam,
                                             float* __restrict__ fidfF,
                                             float* __restrict__ out) {
    __shared__ float2 cb0[128], dd[128];
    __shared__ float  lred[4][16];
    const int n0  = blockIdx.x * 8;
    const int tid = threadIdx.x;
    const float t0 = (float)n0 * DT_F;
    if (tid < 128) {
        float sn, cs;
        sincosf(lam[tid] * t0, &sn, &cs);
        cb0[tid] = make_float2(cs, -sn);
        sincosf(lam[tid] * DT_F, &sn, &cs);
        dd[tid] = make_float2(cs, -sn);
    }
    __syncthreads();

    float ar0=0,ar1=0,ar2=0,ar3=0,ar4=0,ar5=0,ar6=0,ar7=0;
    float ai0=0,ai1=0,ai2=0,ai3=0,ai4=0,ai5=0,ai6=0,ai7=0;
#pragma unroll 4
    for (int i = 0; i < 12; ++i) {
        int e = i * 256 + tid;
        float w = wc[e];
        int pq = ab[e];
        int a = pq >> 7, b = pq & 127;
        float2 ca = cb0[a], cbv = cb0[b];
        float2 da = dd[a],  db  = dd[b];
        float zr = ca.x * cbv.x + ca.y * cbv.y;
        float zi = ca.x * cbv.y - ca.y * cbv.x;
        float fr = da.x * db.x + da.y * db.y;
        float fi = da.x * db.y - da.y * db.x;
        ar0 += w * zr; ai0 += w * zi; { float tr = zr*fr - zi*fi; zi = zr*fi + zi*fr; zr = tr; }
        ar1 += w * zr; ai1 += w * zi; { float tr = zr*fr - zi*fi; zi = zr*fi + zi*fr; zr = tr; }
        ar2 += w * zr; ai2 += w * zi; { float tr = zr*fr - zi*fi; zi = zr*fi + zi*fr; zr = tr; }
        ar3 += w * zr; ai3 += w * zi; { float tr = zr*fr - zi*fi; zi = zr*fi + zi*fr; zr = tr; }
        ar4 += w * zr; ai4 += w * zi; { float tr = zr*fr - zi*fi; zi = zr*fi + zi*fr; zr = tr; }
        ar5 += w * zr; ai5 += w * zi; { float tr = zr*fr - zi*fi; zi = zr*fi + zi*fr; zr = tr; }
        ar6 += w * zr; ai6 += w * zi; { float tr = zr*fr - zi*fi; zi = zr*fi + zi*fr; zr = tr; }
        ar7 += w * zr; ai7 += w * zi;
    }

    const int wave = tid >> 6, lane = tid & 63;
    float acc[16] = {ar0,ai0,ar1,ai1,ar2,ai2,ar3,ai3,ar4,ai4,ar5,ai5,ar6,ai6,ar7,ai7};
#pragma unroll 16
    for (int v = 0; v < 16; ++v) {
        float x = acc[v];
        for (int off = 32; off > 0; off >>= 1) x += __shfl_down(x, off);
        if (lane == 0) lred[wave][v] = x;
    }
    __syncthreads();
    if (tid < 16) {
        float x = lred[0][tid] + lred[1][tid] + lred[2][tid] + lred[3][tid];
        int jj = tid >> 1, c = tid & 1;
        int n = n0 + jj;
        float ap = expf(-(DT_F / T2_F) * (float)n);
        x *= ap;
        fidfF[2 * n + c] = x;
        if (c == 0) out[n] = x;
    }
}

// split-K shifted-spectrum partials: 8 chunks x 32 k-groups
__global__ __launch_bounds__(256) void k_dft(const float2* __restrict__ fidf,
                                             float* __restrict__ part) {
    __shared__ float2 fs[512];
    const int tid = threadIdx.x;
    const int ch  = blockIdx.x >> 5;
    const int kb  = blockIdx.x & 31;
    const int n0  = ch * 512;
    fs[tid]       = fidf[n0 + tid];
    fs[tid + 256] = fidf[n0 + tid + 256];
    __syncthreads();
    const int k = kb * 256 + tid;
    const int K = (k + 4096) & 8191;
    const float C = TWO_PI / 8192.0f;
    int idx = (n0 * K) & 8191;
    float ar = 0.f;
    for (int i = 0; i < 512; ++i) {
        float2 s = fs[i];
        float sn, cs;
        __sincosf(C * (float)idx, &sn, &cs);
        ar += s.x * cs + s.y * sn;
        idx = (idx + K) & 8191;
    }
    part[ch * 8192 + k] = ar;
}

// reduce partials + write axes
__global__ void k_dredax(const float* __restrict__ part, float* __restrict__ out) {
    int i = blockIdx.x * 256 + threadIdx.x;   // 0..8191
    float s = 0.f;
#pragma unroll
    for (int ch = 0; ch < 8; ++ch) s += part[ch * 8192 + i];
    out[8192 + i] = s;
    out[16384 + i] = -0.5f * SW_F + (float)i * (SW_F / (float)(2 * N_SAMP - 1));
    if (i < N_SAMP)
        out[4096 + i] = (float)i * ((N_SAMP / SW_F) / (float)(N_SAMP - 1));
}

extern "C" void kernel_launch(void* const* d_in, const int* in_sizes, int n_in,
                              void* d_out, int out_size, void* d_ws, size_t ws_size,
                              hipStream_t stream) {
    const float* h = (const float*)d_in[0];
    float* out = (float*)d_out;
    float* ws  = (float*)d_ws;

    float*  Vt   = ws;
    float*  lam  = ws + 16384;
    float*  U    = ws + 16512;
    float*  wc   = ws + 49280;
    int*    ab   = (int*)(ws + 52352);
    float*  fidfF= ws + 65664;
    float2* fidf = (float2*)(ws + 65664);
    float*  part = ws + 73856;

    k_eig<<<8, 64, 0, stream>>>(h, Vt, U, lam);
    k_mwc<<<24, 128, 0, stream>>>(Vt, U, wc, ab);
    k_fid<<<512, 256, 0, stream>>>(wc, ab, lam, fidfF, out);
    k_dft<<<256, 256, 0, stream>>>(fidf, part);
    k_dredax<<<32, 256, 0, stream>>>(part, out);
}

// Round 23
// 92.149 us; speedup vs baseline: 1.5003x; 1.5003x over previous
//
#include <hip/hip_runtime.h>
#include <math.h>

#define N_SAMP 4096
#define NS     7
#define DT_F   1e-5f
#define B0_F   80.0f
#define T2_F   1.0f
#define SW_F   1000.0f
#define TWO_PI 6.2831853071795864769f

// ws layout (floats): Vt 0..16384 | lam 16384..16512 | U 16512..32896 |
//                     wc 49280..52352 | ab(int) 52352..55424 |
//                     fidf(float2) 65664..73856 | part 73856..139392
// out (f32, 24576): ReFID [0,4096) | time [4096,8192) |
//                   Re shifted spec [8192,16384) | freq [16384,24576)

// One-sided Jacobi per sector: one WAVE per rotation pair, 16 waves/block.
// Lane l of the pair-wave holds element l of BOTH columns (2 regs); dots via
// shfl_xor butterfly; 1 barrier/round (pairs have disjoint columns).
// r19-r22 (one wave, per-lane columns) showed ~100us from exposed latency;
// this restores multi-wave latency hiding with the same validated math.
__global__ __launch_bounds__(1024) void k_eig(const float* __restrict__ h,
                                              float* __restrict__ Vt_full,
                                              float* __restrict__ U,
                                              float* __restrict__ lam_out) {
    const int nsz_[8]   = {1, 7, 21, 35, 35, 21, 7, 1};
    const int nbase_[8] = {0, 1, 8, 29, 64, 99, 120, 127};
    const int s    = blockIdx.x;
    const int ns   = nsz_[s];
    const int base = nbase_[s];
    const int tid  = threadIdx.x;
    const int wave = tid >> 6;
    const int lane = tid & 63;
    const int m    = ns + 1;          // even; column index ns is padding
    const int nr   = m - 1;           // rounds in one sweep
    const int npairs = m / 2;

    __shared__ float Bl[36 * 37];     // column c at Bl[c*37 + e]
    __shared__ float hs[49];
    __shared__ int   st[36];
    __shared__ int   inv2[128];
    __shared__ float inorm_s[36];

    if (tid < 49) hs[tid] = h[tid];
    if (tid == 0) {
        int cnt = 0;
        for (int r = 0; r < 128; ++r) if (__popc(r) == s) st[cnt++] = r;
    }
    for (int t = tid; t < 36 * 37; t += 1024) Bl[t] = 0.f;
    __syncthreads();
    if (tid < ns) inv2[st[tid]] = tid;

    const float SIGMA = 10000.0f;
    // build B = A_sector + SIGMA*I, column-major (A symmetric)
    for (int e2 = tid; e2 < ns * ns; e2 += 1024) {
        int cidx = e2 / ns, eidx = e2 - cidx * ns;
        int r = st[eidx], c = st[cidx];
        float val = 0.f;
        if (r == c) {
            float acc = 0.f;
            for (int a = 0; a < 7; ++a) {
                float za = ((r >> (6 - a)) & 1) ? -0.5f : 0.5f;
                acc += B0_F * hs[a * 7 + a] * za;
                for (int b = a + 1; b < 7; ++b) {
                    float zb = ((r >> (6 - b)) & 1) ? -0.5f : 0.5f;
                    acc += hs[a * 7 + b] * za * zb;
                }
            }
            val = TWO_PI * acc + SIGMA;
        } else {
            int x = r ^ c;
            if (__popc(x) == 2) {
                int u = 31 - __clz(x);
                int v = __ffs(x) - 1;
                if (((r >> u) & 1) != ((r >> v) & 1))
                    val = TWO_PI * 0.5f * hs[(6 - u) * 7 + (6 - v)];
            }
        }
        Bl[cidx * 37 + eidx] = val;
    }
    __syncthreads();

    if (ns > 1) {
        for (int t = 0; t < nr; ++t) {
#pragma unroll 2
            for (int rep = 0; rep < 2; ++rep) {
                int j = wave + rep * 16;
                if (j < npairs) {                 // wave-uniform
                    int p, q;
                    if (j == 0) { p = t; q = m - 1; }
                    else {
                        int a1 = (t + j) % nr;
                        int b1 = (t + nr - j) % nr;
                        p = a1 < b1 ? a1 : b1;
                        q = a1 < b1 ? b1 : a1;
                    }
                    if (q < ns) {                 // wave-uniform (padding pair skip)
                        float bp = (lane < ns) ? Bl[p * 37 + lane] : 0.f;
                        float bq = (lane < ns) ? Bl[q * 37 + lane] : 0.f;
                        float va = bp * bp, vb = bq * bq, vg = bp * bq;
#pragma unroll
                        for (int off = 32; off > 0; off >>= 1) {
                            va += __shfl_xor(va, off);
                            vb += __shfl_xor(vb, off);
                            vg += __shfl_xor(vg, off);
                        }
                        if (fabsf(vg) >= 1e-20f) {   // wave-uniform
                            float tau = (vb - va) / (2.f * vg);
                            float tt  = copysignf(1.f / (fabsf(tau) + sqrtf(1.f + tau * tau)), tau);
                            float c   = rsqrtf(1.f + tt * tt);
                            float sn  = tt * c;
                            if (lane < ns) {
                                Bl[p * 37 + lane] = c * bp - sn * bq;
                                Bl[q * 37 + lane] = sn * bp + c * bq;
                            }
                        }
                    }
                }
            }
            __syncthreads();
        }
    }

    // eigenvalues + inverse norms (wave-parallel over columns)
    for (int c = wave; c < ns; c += 16) {
        float b = (lane < ns) ? Bl[c * 37 + lane] : 0.f;
        float nn = b * b;
#pragma unroll
        for (int off = 32; off > 0; off >>= 1) nn += __shfl_xor(nn, off);
        if (lane == 0) {
            float nrm = sqrtf(nn);
            lam_out[base + c] = nrm - SIGMA;
            inorm_s[c] = 1.f / nrm;
        }
    }
    __syncthreads();
    // coalesced writeback of Vt rows + fused U rows
    for (int t = tid; t < ns * 128; t += 1024) {
        int a = t >> 7, rr = t & 127;
        float io = inorm_s[a];
        int pc = __popc(rr);
        float v = (pc == s) ? Bl[a * 37 + inv2[rr]] * io : 0.f;
        Vt_full[(base + a) * 128 + rr] = v;
        float uval = 0.f;
        if (pc == s - 1) {
#pragma unroll
            for (int p = 0; p < 7; ++p)
                if (!((rr >> p) & 1)) uval += Bl[a * 37 + inv2[rr + (1 << p)]];
            uval *= io;
        }
        U[(base + a) * 128 + rr] = uval;
    }
}

// Compact W: only sector-pair (s -> s+1) entries are nonzero; 3003 entries,
// padded to 3072. wc[e] = 0.5*(Vt[a]·U[b])^2, ab[e] = (a<<7)|b.
__global__ __launch_bounds__(128) void k_mwc(const float* __restrict__ Vt,
                                             const float* __restrict__ U,
                                             float* __restrict__ wc,
                                             int* __restrict__ ab) {
    const int n2_[7]   = {7, 21, 35, 35, 21, 7, 1};
    const int offs_[7] = {0, 7, 154, 889, 2114, 2849, 2996};
    const int nb1_[7]  = {0, 1, 8, 29, 64, 99, 120};
    const int nb2_[7]  = {1, 8, 29, 64, 99, 120, 127};
    int e = blockIdx.x * 128 + threadIdx.x;
    if (e >= 3072) return;
    if (e >= 3003) { wc[e] = 0.f; ab[e] = 0; return; }
    int s = 0;
#pragma unroll
    for (int t = 1; t < 7; ++t) if (e >= offs_[t]) s = t;
    int loc = e - offs_[s];
    int i = loc / n2_[s];
    int j = loc - i * n2_[s];
    int a = nb1_[s] + i, b = nb2_[s] + j;
    float acc = 0.f;
    for (int r = 0; r < 128; ++r) acc += Vt[a * 128 + r] * U[b * 128 + r];
    wc[e] = 0.5f * acc * acc;
    ab[e] = (a << 7) | b;
}

// 8 samples per block via phasor recurrence over the 3072 compact entries
__global__ __launch_bounds__(256) void k_fid(const float* __restrict__ wc,
                                             const int* __restrict__ ab,
                                             const float* __restrict__ lam,
                                             float* __restrict__ fidfF,
                                             float* __restrict__ out) {
    __shared__ float2 cb0[128], dd[128];
    __shared__ float  lred[4][16];
    const int n0  = blockIdx.x * 8;
    const int tid = threadIdx.x;
    const float t0 = (float)n0 * DT_F;
    if (tid < 128) {
        float sn, cs;
        sincosf(lam[tid] * t0, &sn, &cs);
        cb0[tid] = make_float2(cs, -sn);
        sincosf(lam[tid] * DT_F, &sn, &cs);
        dd[tid] = make_float2(cs, -sn);
    }
    __syncthreads();

    float ar0=0,ar1=0,ar2=0,ar3=0,ar4=0,ar5=0,ar6=0,ar7=0;
    float ai0=0,ai1=0,ai2=0,ai3=0,ai4=0,ai5=0,ai6=0,ai7=0;
#pragma unroll 4
    for (int i = 0; i < 12; ++i) {
        int e = i * 256 + tid;
        float w = wc[e];
        int pq = ab[e];
        int a = pq >> 7, b = pq & 127;
        float2 ca = cb0[a], cbv = cb0[b];
        float2 da = dd[a],  db  = dd[b];
        float zr = ca.x * cbv.x + ca.y * cbv.y;
        float zi = ca.x * cbv.y - ca.y * cbv.x;
        float fr = da.x * db.x + da.y * db.y;
        float fi = da.x * db.y - da.y * db.x;
        ar0 += w * zr; ai0 += w * zi; { float tr = zr*fr - zi*fi; zi = zr*fi + zi*fr; zr = tr; }
        ar1 += w * zr; ai1 += w * zi; { float tr = zr*fr - zi*fi; zi = zr*fi + zi*fr; zr = tr; }
        ar2 += w * zr; ai2 += w * zi; { float tr = zr*fr - zi*fi; zi = zr*fi + zi*fr; zr = tr; }
        ar3 += w * zr; ai3 += w * zi; { float tr = zr*fr - zi*fi; zi = zr*fi + zi*fr; zr = tr; }
        ar4 += w * zr; ai4 += w * zi; { float tr = zr*fr - zi*fi; zi = zr*fi + zi*fr; zr = tr; }
        ar5 += w * zr; ai5 += w * zi; { float tr = zr*fr - zi*fi; zi = zr*fi + zi*fr; zr = tr; }
        ar6 += w * zr; ai6 += w * zi; { float tr = zr*fr - zi*fi; zi = zr*fi + zi*fr; zr = tr; }
        ar7 += w * zr; ai7 += w * zi;
    }

    const int wave = tid >> 6, lane = tid & 63;
    float acc[16] = {ar0,ai0,ar1,ai1,ar2,ai2,ar3,ai3,ar4,ai4,ar5,ai5,ar6,ai6,ar7,ai7};
#pragma unroll 16
    for (int v = 0; v < 16; ++v) {
        float x = acc[v];
        for (int off = 32; off > 0; off >>= 1) x += __shfl_down(x, off);
        if (lane == 0) lred[wave][v] = x;
    }
    __syncthreads();
    if (tid < 16) {
        float x = lred[0][tid] + lred[1][tid] + lred[2][tid] + lred[3][tid];
        int jj = tid >> 1, c = tid & 1;
        int n = n0 + jj;
        float ap = expf(-(DT_F / T2_F) * (float)n);
        x *= ap;
        fidfF[2 * n + c] = x;
        if (c == 0) out[n] = x;
    }
}

// split-K shifted-spectrum partials: 8 chunks x 32 k-groups
__global__ __launch_bounds__(256) void k_dft(const float2* __restrict__ fidf,
                                             float* __restrict__ part) {
    __shared__ float2 fs[512];
    const int tid = threadIdx.x;
    const int ch  = blockIdx.x >> 5;
    const int kb  = blockIdx.x & 31;
    const int n0  = ch * 512;
    fs[tid]       = fidf[n0 + tid];
    fs[tid + 256] = fidf[n0 + tid + 256];
    __syncthreads();
    const int k = kb * 256 + tid;
    const int K = (k + 4096) & 8191;
    const float C = TWO_PI / 8192.0f;
    int idx = (n0 * K) & 8191;
    float ar = 0.f;
    for (int i = 0; i < 512; ++i) {
        float2 s = fs[i];
        float sn, cs;
        __sincosf(C * (float)idx, &sn, &cs);
        ar += s.x * cs + s.y * sn;
        idx = (idx + K) & 8191;
    }
    part[ch * 8192 + k] = ar;
}

// reduce partials + write axes
__global__ void k_dredax(const float* __restrict__ part, float* __restrict__ out) {
    int i = blockIdx.x * 256 + threadIdx.x;   // 0..8191
    float s = 0.f;
#pragma unroll
    for (int ch = 0; ch < 8; ++ch) s += part[ch * 8192 + i];
    out[8192 + i] = s;
    out[16384 + i] = -0.5f * SW_F + (float)i * (SW_F / (float)(2 * N_SAMP - 1));
    if (i < N_SAMP)
        out[4096 + i] = (float)i * ((N_SAMP / SW_F) / (float)(N_SAMP - 1));
}

extern "C" void kernel_launch(void* const* d_in, const int* in_sizes, int n_in,
                              void* d_out, int out_size, void* d_ws, size_t ws_size,
                              hipStream_t stream) {
    const float* h = (const float*)d_in[0];
    float* out = (float*)d_out;
    float* ws  = (float*)d_ws;

    float*  Vt   = ws;
    float*  lam  = ws + 16384;
    float*  U    = ws + 16512;
    float*  wc   = ws + 49280;
    int*    ab   = (int*)(ws + 52352);
    float*  fidfF= ws + 65664;
    float2* fidf = (float2*)(ws + 65664);
    float*  part = ws + 73856;

    k_eig<<<8, 1024, 0, stream>>>(h, Vt, U, lam);
    k_mwc<<<24, 128, 0, stream>>>(Vt, U, wc, ab);
    k_fid<<<512, 256, 0, stream>>>(wc, ab, lam, fidfF, out);
    k_dft<<<256, 256, 0, stream>>>(fidf, part);
    k_dredax<<<32, 256, 0, stream>>>(part, out);
}

// Round 24
// 79.993 us; speedup vs baseline: 1.7283x; 1.1520x over previous
//
#include <hip/hip_runtime.h>
#include <math.h>

#define N_SAMP 4096
#define NS     7
#define DT_F   1e-5f
#define B0_F   80.0f
#define T2_F   1.0f
#define SW_F   1000.0f
#define TWO_PI 6.2831853071795864769f
#define NSWEEP_S 1
#define EIG_T  1024   // 16 waves: rep0 -> pairs 0..15, rep1 -> pairs 16..17

// ws layout (floats): Vc 0..3432 | Uc 4096..7099 | lam 16384..16512 |
//                     wc 49280..52352 | ab(int) 52352..55424 |
//                     fidf(float2) 65664..73856 | part 73856..139392
// out (f32, 24576): ReFID [0,4096) | time [4096,8192) |
//                   Re shifted spec [8192,16384) | freq [16384,24576)
//
// Compact layouts (sector sizes nsz[s]=C(7,s)):
//   Vc: sector s block at cum2[s], row a_local (len ns): V^T on sector-s states
//   Uc: b in sector s -> row at offsU[s] + b_local*nsz[s-1], support = sector s-1
//       (offsU[s] == offs_[s-1] of k_mwc; total 3003)

__global__ __launch_bounds__(EIG_T) void k_eig(const float* __restrict__ h,
                                               float* __restrict__ Vc,
                                               float* __restrict__ Uc,
                                               float* __restrict__ lam_out) {
    const int nsz_[8]   = {1, 7, 21, 35, 35, 21, 7, 1};
    const int nbase_[8] = {0, 1, 8, 29, 64, 99, 120, 127};
    const int cum2_[8]  = {0, 1, 50, 491, 1716, 2941, 3382, 3431};
    const int offsU_[8] = {0, 0, 7, 154, 889, 2114, 2849, 2996}; // s>=1
    const int s    = blockIdx.x;
    const int ns   = nsz_[s];
    const int base = nbase_[s];
    const int tid  = threadIdx.x;
    const int wave = tid >> 6;
    const int lane = tid & 63;

    __shared__ float As[36 * 37];
    __shared__ float Vs[36 * 37];
    __shared__ int   st[36];
    __shared__ int   stm1[36];
    __shared__ int   inv[128];
    __shared__ float hs[49];
    __shared__ int   ppt[35 * 18];    // tournament table: (p<<8)|q per (round, pair)

    const int m      = ns + 1;        // sector sizes odd -> m even
    const int nr     = m - 1;
    const int npairs = m / 2;
    const int ksm1   = (s >= 1) ? nsz_[s - 1] : 0;

    if (tid < 49) hs[tid] = h[tid];
    if (tid == 0) {
        int cnt = 0;
        for (int r = 0; r < 128; ++r) if (__popc(r) == s) st[cnt++] = r;
    }
    if (tid == 1 && s >= 1) {
        int cnt = 0;
        for (int r = 0; r < 128; ++r) if (__popc(r) == s - 1) stm1[cnt++] = r;
    }
    if (tid < 128 && __popc(tid) == s) {
        int cnt = 0;
        for (int r = 0; r < 128; ++r) { if (r == tid) break; if (__popc(r) == s) ++cnt; }
        inv[tid] = cnt;
    }
    if (ns > 1) {
        for (int e = tid; e < nr * npairs; e += EIG_T) {
            int t = e / npairs, j = e - t * npairs;
            int p, q;
            if (j == 0) { p = t; q = m - 1; }
            else {
                int a1 = (t + j) % nr;
                int b1 = (t + nr - j) % nr;
                p = a1 < b1 ? a1 : b1;
                q = a1 < b1 ? b1 : a1;
            }
            ppt[t * npairs + j] = (p << 8) | q;
        }
    }
    for (int t = tid; t < 36 * 37; t += EIG_T) { As[t] = 0.f; Vs[t] = 0.f; }
    __syncthreads();

    // Build sector Hamiltonian from h
    for (int t = tid; t < ns * ns; t += EIG_T) {
        int i = t / ns, j = t % ns;
        int r = st[i], c = st[j];
        float val = 0.f;
        if (r == c) {
            float acc = 0.f;
            for (int a = 0; a < 7; ++a) {
                float za = ((r >> (6 - a)) & 1) ? -0.5f : 0.5f;
                acc += B0_F * hs[a * 7 + a] * za;
                for (int b = a + 1; b < 7; ++b) {
                    float zb = ((r >> (6 - b)) & 1) ? -0.5f : 0.5f;
                    acc += hs[a * 7 + b] * za * zb;
                }
            }
            val = TWO_PI * acc;
        } else {
            int x = r ^ c;
            if (__popc(x) == 2) {
                int u = 31 - __clz(x);
                int v = __ffs(x) - 1;
                if (((r >> u) & 1) != ((r >> v) & 1))
                    val = TWO_PI * 0.5f * hs[(6 - u) * 7 + (6 - v)];
            }
        }
        As[i * 37 + j] = val;
    }
    for (int i = tid; i < ns; i += EIG_T) Vs[i * 37 + i] = 1.f;
    __syncthreads();

    if (ns > 1) {
        for (int sweep = 0; sweep < NSWEEP_S; ++sweep) {
            for (int t = 0; t < nr; ++t) {
                const int* prow = &ppt[t * npairs];
                float c0 = 1.f, s0 = 0.f, c1 = 1.f, s1 = 0.f;
                int   pq0 = -1, pq1 = -1;

                // ---- phase R: A-rows + V-rows; (c,s) computed in-wave, kept in regs
#pragma unroll 2
                for (int rep = 0; rep < 2; ++rep) {
                    int jj = wave + rep * 16;
                    if (jj < npairs) {
                        int pq = prow[jj];
                        int p = pq >> 8, q = pq & 255;
                        if (q < ns) {
                            float app = As[p * 37 + p];
                            float aqq = As[q * 37 + q];
                            float apq = As[p * 37 + q];
                            float c = 1.f, sn = 0.f;
                            if (fabsf(apq) >= 1e-30f) {
                                float tau = (aqq - app) / (2.f * apq);
                                float tt  = copysignf(1.f / (fabsf(tau) + sqrtf(1.f + tau * tau)), tau);
                                c  = rsqrtf(1.f + tt * tt);
                                sn = tt * c;
                            }
                            if (rep == 0) { c0 = c; s0 = sn; pq0 = pq; }
                            else          { c1 = c; s1 = sn; pq1 = pq; }
                            if (lane < ns) {
                                float ap = As[p * 37 + lane], aq = As[q * 37 + lane];
                                As[p * 37 + lane] = c * ap - sn * aq;
                                As[q * 37 + lane] = sn * ap + c * aq;
                                float vp = Vs[p * 37 + lane], vq = Vs[q * 37 + lane];
                                Vs[p * 37 + lane] = c * vp - sn * vq;
                                Vs[q * 37 + lane] = sn * vp + c * vq;
                            }
                        }
                    }
                }
                __syncthreads();
                // ---- phase C: A-cols (registered (c,s))
                if (pq0 >= 0) {
                    int p = pq0 >> 8, q = pq0 & 255;
                    if (q < ns && lane < ns) {
                        float ap = As[lane * 37 + p], aq = As[lane * 37 + q];
                        As[lane * 37 + p] = c0 * ap - s0 * aq;
                        As[lane * 37 + q] = s0 * ap + c0 * aq;
                    }
                }
                if (pq1 >= 0) {
                    int p = pq1 >> 8, q = pq1 & 255;
                    if (q < ns && lane < ns) {
                        float ap = As[lane * 37 + p], aq = As[lane * 37 + q];
                        As[lane * 37 + p] = c1 * ap - s1 * aq;
                        As[lane * 37 + q] = s1 * ap + c1 * aq;
                    }
                }
                __syncthreads();
            }
        }
    }

    for (int i = tid; i < ns; i += EIG_T) lam_out[base + i] = As[i * 37 + i];
    // compact Vc writeback: Vc[cum2[s] + a*ns + k] = Vs[a*37 + k]
    for (int t = tid; t < ns * ns; t += EIG_T) {
        int a = t / ns, k = t - (t / ns) * ns;
        Vc[cum2_[s] + t] = Vs[a * 37 + k];
    }
    // compact Uc writeback: b=(base+a), support = sector s-1 states stm1[i]
    if (s >= 1) {
        for (int t = tid; t < ns * ksm1; t += EIG_T) {
            int a = t / ksm1, i = t - (t / ksm1) * ksm1;
            int rr = stm1[i];
            float uval = 0.f;
#pragma unroll
            for (int p = 0; p < 7; ++p)
                if (!((rr >> p) & 1)) uval += Vs[a * 37 + inv[rr + (1 << p)]];
            Uc[offsU_[s] + t] = uval;
        }
    }
}

// Compact W from compact Vc/Uc: pair-sector t (a in sector t, b in sector t+1),
// dot over the n1=C(7,t) shared-support states. 3003 entries padded to 3072.
__global__ __launch_bounds__(128) void k_mwc(const float* __restrict__ Vc,
                                             const float* __restrict__ Uc,
                                             float* __restrict__ wc,
                                             int* __restrict__ ab) {
    const int n1_[7]   = {1, 7, 21, 35, 35, 21, 7};
    const int n2_[7]   = {7, 21, 35, 35, 21, 7, 1};
    const int offs_[7] = {0, 7, 154, 889, 2114, 2849, 2996};
    const int nb1_[7]  = {0, 1, 8, 29, 64, 99, 120};
    const int nb2_[7]  = {1, 8, 29, 64, 99, 120, 127};
    const int cum2_[7] = {0, 1, 50, 491, 1716, 2941, 3382};
    int e = blockIdx.x * 128 + threadIdx.x;
    if (e >= 3072) return;
    if (e >= 3003) { wc[e] = 0.f; ab[e] = 0; return; }
    int t = 0;
#pragma unroll
    for (int u = 1; u < 7; ++u) if (e >= offs_[u]) t = u;
    int loc = e - offs_[t];
    int n1 = n1_[t], n2 = n2_[t];
    int i = loc / n2;
    int j = loc - i * n2;
    const float* va = &Vc[cum2_[t] + i * n1];
    const float* ub = &Uc[offs_[t] + j * n1];
    float acc = 0.f;
    for (int k = 0; k < n1; ++k) acc += va[k] * ub[k];
    wc[e] = 0.5f * acc * acc;
    ab[e] = ((nb1_[t] + i) << 7) | (nb2_[t] + j);
}

// 8 samples per block via phasor recurrence over the 3072 compact entries
__global__ __launch_bounds__(256) void k_fid(const float* __restrict__ wc,
                                             const int* __restrict__ ab,
                                             const float* __restrict__ lam,
                                             float* __restrict__ fidfF,
                                             float* __restrict__ out) {
    __shared__ float2 cb0[128], dd[128];
    __shared__ float  lred[4][16];
    const int n0  = blockIdx.x * 8;
    const int tid = threadIdx.x;
    const float t0 = (float)n0 * DT_F;
    if (tid < 128) {
        float sn, cs;
        sincosf(lam[tid] * t0, &sn, &cs);
        cb0[tid] = make_float2(cs, -sn);
        sincosf(lam[tid] * DT_F, &sn, &cs);
        dd[tid] = make_float2(cs, -sn);
    }
    __syncthreads();

    float ar0=0,ar1=0,ar2=0,ar3=0,ar4=0,ar5=0,ar6=0,ar7=0;
    float ai0=0,ai1=0,ai2=0,ai3=0,ai4=0,ai5=0,ai6=0,ai7=0;
#pragma unroll 4
    for (int i = 0; i < 12; ++i) {
        int e = i * 256 + tid;
        float w = wc[e];
        int pq = ab[e];
        int a = pq >> 7, b = pq & 127;
        float2 ca = cb0[a], cbv = cb0[b];
        float2 da = dd[a],  db  = dd[b];
        float zr = ca.x * cbv.x + ca.y * cbv.y;
        float zi = ca.x * cbv.y - ca.y * cbv.x;
        float fr = da.x * db.x + da.y * db.y;
        float fi = da.x * db.y - da.y * db.x;
        ar0 += w * zr; ai0 += w * zi; { float tr = zr*fr - zi*fi; zi = zr*fi + zi*fr; zr = tr; }
        ar1 += w * zr; ai1 += w * zi; { float tr = zr*fr - zi*fi; zi = zr*fi + zi*fr; zr = tr; }
        ar2 += w * zr; ai2 += w * zi; { float tr = zr*fr - zi*fi; zi = zr*fi + zi*fr; zr = tr; }
        ar3 += w * zr; ai3 += w * zi; { float tr = zr*fr - zi*fi; zi = zr*fi + zi*fr; zr = tr; }
        ar4 += w * zr; ai4 += w * zi; { float tr = zr*fr - zi*fi; zi = zr*fi + zi*fr; zr = tr; }
        ar5 += w * zr; ai5 += w * zi; { float tr = zr*fr - zi*fi; zi = zr*fi + zi*fr; zr = tr; }
        ar6 += w * zr; ai6 += w * zi; { float tr = zr*fr - zi*fi; zi = zr*fi + zi*fr; zr = tr; }
        ar7 += w * zr; ai7 += w * zi;
    }

    const int wave = tid >> 6, lane = tid & 63;
    float acc[16] = {ar0,ai0,ar1,ai1,ar2,ai2,ar3,ai3,ar4,ai4,ar5,ai5,ar6,ai6,ar7,ai7};
#pragma unroll 16
    for (int v = 0; v < 16; ++v) {
        float x = acc[v];
        for (int off = 32; off > 0; off >>= 1) x += __shfl_down(x, off);
        if (lane == 0) lred[wave][v] = x;
    }
    __syncthreads();
    if (tid < 16) {
        float x = lred[0][tid] + lred[1][tid] + lred[2][tid] + lred[3][tid];
        int jj = tid >> 1, c = tid & 1;
        int n = n0 + jj;
        float ap = expf(-(DT_F / T2_F) * (float)n);
        x *= ap;
        fidfF[2 * n + c] = x;
        if (c == 0) out[n] = x;
    }
}

// split-K shifted-spectrum partials: 8 chunks x 32 k-groups
__global__ __launch_bounds__(256) void k_dft(const float2* __restrict__ fidf,
                                             float* __restrict__ part) {
    __shared__ float2 fs[512];
    const int tid = threadIdx.x;
    const int ch  = blockIdx.x >> 5;
    const int kb  = blockIdx.x & 31;
    const int n0  = ch * 512;
    fs[tid]       = fidf[n0 + tid];
    fs[tid + 256] = fidf[n0 + tid + 256];
    __syncthreads();
    const int k = kb * 256 + tid;
    const int K = (k + 4096) & 8191;
    const float C = TWO_PI / 8192.0f;
    int idx = (n0 * K) & 8191;
    float ar = 0.f;
    for (int i = 0; i < 512; ++i) {
        float2 s = fs[i];
        float sn, cs;
        __sincosf(C * (float)idx, &sn, &cs);
        ar += s.x * cs + s.y * sn;
        idx = (idx + K) & 8191;
    }
    part[ch * 8192 + k] = ar;
}

// reduce partials + write axes
__global__ void k_dredax(const float* __restrict__ part, float* __restrict__ out) {
    int i = blockIdx.x * 256 + threadIdx.x;   // 0..8191
    float s = 0.f;
#pragma unroll
    for (int ch = 0; ch < 8; ++ch) s += part[ch * 8192 + i];
    out[8192 + i] = s;
    out[16384 + i] = -0.5f * SW_F + (float)i * (SW_F / (float)(2 * N_SAMP - 1));
    if (i < N_SAMP)
        out[4096 + i] = (float)i * ((N_SAMP / SW_F) / (float)(N_SAMP - 1));
}

extern "C" void kernel_launch(void* const* d_in, const int* in_sizes, int n_in,
                              void* d_out, int out_size, void* d_ws, size_t ws_size,
                              hipStream_t stream) {
    const float* h = (const float*)d_in[0];
    float* out = (float*)d_out;
    float* ws  = (float*)d_ws;

    float*  Vc   = ws;
    float*  Uc   = ws + 4096;
    float*  lam  = ws + 16384;
    float*  wc   = ws + 49280;
    int*    ab   = (int*)(ws + 52352);
    float*  fidfF= ws + 65664;
    float2* fidf = (float2*)(ws + 65664);
    float*  part = ws + 73856;

    k_eig<<<8, EIG_T, 0, stream>>>(h, Vc, Uc, lam);
    k_mwc<<<24, 128, 0, stream>>>(Vc, Uc, wc, ab);
    k_fid<<<512, 256, 0, stream>>>(wc, ab, lam, fidfF, out);
    k_dft<<<256, 256, 0, stream>>>(fidf, part);
    k_dredax<<<32, 256, 0, stream>>>(part, out);
}

// Round 25
// 65.837 us; speedup vs baseline: 2.0999x; 1.2150x over previous
//
#include <hip/hip_runtime.h>
#include <math.h>

#define N_SAMP 4096
#define NS     7
#define DT_F   1e-5f
#define B0_F   80.0f
#define T2_F   1.0f
#define SW_F   1000.0f
#define TWO_PI 6.2831853071795864769f
#define EIG_T  1024

// ws layout (floats): Vc 0..3432 | Uc 4096..7099 | lam 16384..16512 |
//                     wc 49280..52352 | ab(int) 52352..55424 |
//                     fidf(float2) 65664..73856 | part 73856..139392
// out (f32, 24576): ReFID [0,4096) | time [4096,8192) |
//                   Re shifted spec [8192,16384) | freq [16384,24576)

// Sector eigensolver, two-sided Jacobi, SPARSITY-AWARE sweep:
// A_pq != 0 only for flip-flop pairs (one (i,j) bit swap). Edge-color by
// bit-pair: 21 rounds, each a disjoint matching of <=10 pairs (1 wave/pair).
// Replaces the 35-round full tournament (r24: 44.6us) with same residual
// class (fill-in is O(eps^2), below the validated 1-sweep noise floor).
__global__ __launch_bounds__(EIG_T) void k_eig(const float* __restrict__ h,
                                               float* __restrict__ Vc,
                                               float* __restrict__ Uc,
                                               float* __restrict__ lam_out) {
    const int nsz_[8]   = {1, 7, 21, 35, 35, 21, 7, 1};
    const int nbase_[8] = {0, 1, 8, 29, 64, 99, 120, 127};
    const int cum2_[8]  = {0, 1, 50, 491, 1716, 2941, 3382, 3431};
    const int offsU_[8] = {0, 0, 7, 154, 889, 2114, 2849, 2996}; // s>=1
    const int s    = blockIdx.x;
    const int ns   = nsz_[s];
    const int base = nbase_[s];
    const int tid  = threadIdx.x;
    const int wave = tid >> 6;
    const int lane = tid & 63;

    __shared__ float As[36 * 37];
    __shared__ float Vs[36 * 37];
    __shared__ int   st[36];
    __shared__ int   stm1[36];
    __shared__ int   inv[128];
    __shared__ float hs[49];
    __shared__ int   ppt2[21 * 12];   // bit-pair-colored pair lists
    __shared__ int   cnt2[21];

    const int ksm1 = (s >= 1) ? nsz_[s - 1] : 0;

    if (tid < 49) hs[tid] = h[tid];
    if (tid < 21) cnt2[tid] = 0;
    if (tid == 0) {
        int cnt = 0;
        for (int r = 0; r < 128; ++r) if (__popc(r) == s) st[cnt++] = r;
    }
    if (tid == 1 && s >= 1) {
        int cnt = 0;
        for (int r = 0; r < 128; ++r) if (__popc(r) == s - 1) stm1[cnt++] = r;
    }
    if (tid < 128 && __popc(tid) == s) {
        int cnt = 0;
        for (int r = 0; r < 128; ++r) { if (r == tid) break; if (__popc(r) == s) ++cnt; }
        inv[tid] = cnt;
    }
    for (int t = tid; t < 36 * 37; t += EIG_T) { As[t] = 0.f; Vs[t] = 0.f; }
    __syncthreads();

    // build the 21 matchings: round rid(i<j) holds pairs (inv[r], inv[r^m])
    // for states r with bit_i=1, bit_j=0 (each connected edge appears once)
    if (ns > 1) {
        const int off_[7] = {0, 6, 11, 15, 18, 20, 0};
        for (int r = tid; r < 128; r += EIG_T) {
            if (__popc(r) == s) {
                for (int i = 0; i < 6; ++i) {
                    if (!((r >> i) & 1)) continue;
                    for (int j = i + 1; j < 7; ++j) {
                        if ((r >> j) & 1) continue;
                        int rid = off_[i] + (j - i - 1);
                        int prt = r ^ ((1 << i) | (1 << j));
                        int slot = atomicAdd(&cnt2[rid], 1);
                        ppt2[rid * 12 + slot] = (inv[r] << 8) | inv[prt];
                    }
                }
            }
        }
    }

    // Build sector Hamiltonian from h
    for (int t = tid; t < ns * ns; t += EIG_T) {
        int i = t / ns, j = t % ns;
        int r = st[i], c = st[j];
        float val = 0.f;
        if (r == c) {
            float acc = 0.f;
            for (int a = 0; a < 7; ++a) {
                float za = ((r >> (6 - a)) & 1) ? -0.5f : 0.5f;
                acc += B0_F * hs[a * 7 + a] * za;
                for (int b = a + 1; b < 7; ++b) {
                    float zb = ((r >> (6 - b)) & 1) ? -0.5f : 0.5f;
                    acc += hs[a * 7 + b] * za * zb;
                }
            }
            val = TWO_PI * acc;
        } else {
            int x = r ^ c;
            if (__popc(x) == 2) {
                int u = 31 - __clz(x);
                int v = __ffs(x) - 1;
                if (((r >> u) & 1) != ((r >> v) & 1))
                    val = TWO_PI * 0.5f * hs[(6 - u) * 7 + (6 - v)];
            }
        }
        As[i * 37 + j] = val;
    }
    for (int i = tid; i < ns; i += EIG_T) Vs[i * 37 + i] = 1.f;
    __syncthreads();

    if (ns > 1) {
        for (int t = 0; t < 21; ++t) {
            int npr = cnt2[t];
            float c0 = 1.f, s0 = 0.f;
            int   pq0 = -1;
            // ---- phase R: A-rows + V-rows; (c,s) in-wave, registered
            if (wave < npr) {
                int pq = ppt2[t * 12 + wave];
                int p = pq >> 8, q = pq & 255;
                float app = As[p * 37 + p];
                float aqq = As[q * 37 + q];
                float apq = As[p * 37 + q];
                float c = 1.f, sn = 0.f;
                if (fabsf(apq) >= 1e-30f) {
                    float tau = (aqq - app) / (2.f * apq);
                    float tt  = copysignf(1.f / (fabsf(tau) + sqrtf(1.f + tau * tau)), tau);
                    c  = rsqrtf(1.f + tt * tt);
                    sn = tt * c;
                }
                c0 = c; s0 = sn; pq0 = pq;
                if (lane < ns) {
                    float ap = As[p * 37 + lane], aq = As[q * 37 + lane];
                    As[p * 37 + lane] = c * ap - sn * aq;
                    As[q * 37 + lane] = sn * ap + c * aq;
                    float vp = Vs[p * 37 + lane], vq = Vs[q * 37 + lane];
                    Vs[p * 37 + lane] = c * vp - sn * vq;
                    Vs[q * 37 + lane] = sn * vp + c * vq;
                }
            }
            __syncthreads();
            // ---- phase C: A-cols (registered (c,s))
            if (pq0 >= 0) {
                int p = pq0 >> 8, q = pq0 & 255;
                if (lane < ns) {
                    float ap = As[lane * 37 + p], aq = As[lane * 37 + q];
                    As[lane * 37 + p] = c0 * ap - s0 * aq;
                    As[lane * 37 + q] = s0 * ap + c0 * aq;
                }
            }
            __syncthreads();
        }
    }

    for (int i = tid; i < ns; i += EIG_T) lam_out[base + i] = As[i * 37 + i];
    // compact Vc writeback: Vc[cum2[s] + a*ns + k] = Vs[a*37 + k]
    for (int t = tid; t < ns * ns; t += EIG_T) {
        int a = t / ns, k = t - (t / ns) * ns;
        Vc[cum2_[s] + t] = Vs[a * 37 + k];
    }
    // compact Uc writeback: b=(base+a), support = sector s-1 states stm1[i]
    if (s >= 1) {
        for (int t = tid; t < ns * ksm1; t += EIG_T) {
            int a = t / ksm1, i = t - (t / ksm1) * ksm1;
            int rr = stm1[i];
            float uval = 0.f;
#pragma unroll
            for (int p = 0; p < 7; ++p)
                if (!((rr >> p) & 1)) uval += Vs[a * 37 + inv[rr + (1 << p)]];
            Uc[offsU_[s] + t] = uval;
        }
    }
}

// Compact W from compact Vc/Uc: pair-sector t (a in sector t, b in sector t+1),
// dot over the n1=C(7,t) shared-support states. 3003 entries padded to 3072.
__global__ __launch_bounds__(128) void k_mwc(const float* __restrict__ Vc,
                                             const float* __restrict__ Uc,
                                             float* __restrict__ wc,
                                             int* __restrict__ ab) {
    const int n1_[7]   = {1, 7, 21, 35, 35, 21, 7};
    const int n2_[7]   = {7, 21, 35, 35, 21, 7, 1};
    const int offs_[7] = {0, 7, 154, 889, 2114, 2849, 2996};
    const int nb1_[7]  = {0, 1, 8, 29, 64, 99, 120};
    const int nb2_[7]  = {1, 8, 29, 64, 99, 120, 127};
    const int cum2_[7] = {0, 1, 50, 491, 1716, 2941, 3382};
    int e = blockIdx.x * 128 + threadIdx.x;
    if (e >= 3072) return;
    if (e >= 3003) { wc[e] = 0.f; ab[e] = 0; return; }
    int t = 0;
#pragma unroll
    for (int u = 1; u < 7; ++u) if (e >= offs_[u]) t = u;
    int loc = e - offs_[t];
    int n1 = n1_[t], n2 = n2_[t];
    int i = loc / n2;
    int j = loc - i * n2;
    const float* va = &Vc[cum2_[t] + i * n1];
    const float* ub = &Uc[offs_[t] + j * n1];
    float acc = 0.f;
    for (int k = 0; k < n1; ++k) acc += va[k] * ub[k];
    wc[e] = 0.5f * acc * acc;
    ab[e] = ((nb1_[t] + i) << 7) | (nb2_[t] + j);
}

// 8 samples per block via phasor recurrence over the 3072 compact entries
__global__ __launch_bounds__(256) void k_fid(const float* __restrict__ wc,
                                             const int* __restrict__ ab,
                                             const float* __restrict__ lam,
                                             float* __restrict__ fidfF,
                                             float* __restrict__ out) {
    __shared__ float2 cb0[128], dd[128];
    __shared__ float  lred[4][16];
    const int n0  = blockIdx.x * 8;
    const int tid = threadIdx.x;
    const float t0 = (float)n0 * DT_F;
    if (tid < 128) {
        float sn, cs;
        sincosf(lam[tid] * t0, &sn, &cs);
        cb0[tid] = make_float2(cs, -sn);
        sincosf(lam[tid] * DT_F, &sn, &cs);
        dd[tid] = make_float2(cs, -sn);
    }
    __syncthreads();

    float ar0=0,ar1=0,ar2=0,ar3=0,ar4=0,ar5=0,ar6=0,ar7=0;
    float ai0=0,ai1=0,ai2=0,ai3=0,ai4=0,ai5=0,ai6=0,ai7=0;
#pragma unroll 4
    for (int i = 0; i < 12; ++i) {
        int e = i * 256 + tid;
        float w = wc[e];
        int pq = ab[e];
        int a = pq >> 7, b = pq & 127;
        float2 ca = cb0[a], cbv = cb0[b];
        float2 da = dd[a],  db  = dd[b];
        float zr = ca.x * cbv.x + ca.y * cbv.y;
        float zi = ca.x * cbv.y - ca.y * cbv.x;
        float fr = da.x * db.x + da.y * db.y;
        float fi = da.x * db.y - da.y * db.x;
        ar0 += w * zr; ai0 += w * zi; { float tr = zr*fr - zi*fi; zi = zr*fi + zi*fr; zr = tr; }
        ar1 += w * zr; ai1 += w * zi; { float tr = zr*fr - zi*fi; zi = zr*fi + zi*fr; zr = tr; }
        ar2 += w * zr; ai2 += w * zi; { float tr = zr*fr - zi*fi; zi = zr*fi + zi*fr; zr = tr; }
        ar3 += w * zr; ai3 += w * zi; { float tr = zr*fr - zi*fi; zi = zr*fi + zi*fr; zr = tr; }
        ar4 += w * zr; ai4 += w * zi; { float tr = zr*fr - zi*fi; zi = zr*fi + zi*fr; zr = tr; }
        ar5 += w * zr; ai5 += w * zi; { float tr = zr*fr - zi*fi; zi = zr*fi + zi*fr; zr = tr; }
        ar6 += w * zr; ai6 += w * zi; { float tr = zr*fr - zi*fi; zi = zr*fi + zi*fr; zr = tr; }
        ar7 += w * zr; ai7 += w * zi;
    }

    const int wave = tid >> 6, lane = tid & 63;
    float acc[16] = {ar0,ai0,ar1,ai1,ar2,ai2,ar3,ai3,ar4,ai4,ar5,ai5,ar6,ai6,ar7,ai7};
#pragma unroll 16
    for (int v = 0; v < 16; ++v) {
        float x = acc[v];
        for (int off = 32; off > 0; off >>= 1) x += __shfl_down(x, off);
        if (lane == 0) lred[wave][v] = x;
    }
    __syncthreads();
    if (tid < 16) {
        float x = lred[0][tid] + lred[1][tid] + lred[2][tid] + lred[3][tid];
        int jj = tid >> 1, c = tid & 1;
        int n = n0 + jj;
        float ap = expf(-(DT_F / T2_F) * (float)n);
        x *= ap;
        fidfF[2 * n + c] = x;
        if (c == 0) out[n] = x;
    }
}

// split-K shifted-spectrum partials: 8 chunks x 32 k-groups
__global__ __launch_bounds__(256) void k_dft(const float2* __restrict__ fidf,
                                             float* __restrict__ part) {
    __shared__ float2 fs[512];
    const int tid = threadIdx.x;
    const int ch  = blockIdx.x >> 5;
    const int kb  = blockIdx.x & 31;
    const int n0  = ch * 512;
    fs[tid]       = fidf[n0 + tid];
    fs[tid + 256] = fidf[n0 + tid + 256];
    __syncthreads();
    const int k = kb * 256 + tid;
    const int K = (k + 4096) & 8191;
    const float C = TWO_PI / 8192.0f;
    int idx = (n0 * K) & 8191;
    float ar = 0.f;
    for (int i = 0; i < 512; ++i) {
        float2 s = fs[i];
        float sn, cs;
        __sincosf(C * (float)idx, &sn, &cs);
        ar += s.x * cs + s.y * sn;
        idx = (idx + K) & 8191;
    }
    part[ch * 8192 + k] = ar;
}

// reduce partials + write axes
__global__ void k_dredax(const float* __restrict__ part, float* __restrict__ out) {
    int i = blockIdx.x * 256 + threadIdx.x;   // 0..8191
    float s = 0.f;
#pragma unroll
    for (int ch = 0; ch < 8; ++ch) s += part[ch * 8192 + i];
    out[8192 + i] = s;
    out[16384 + i] = -0.5f * SW_F + (float)i * (SW_F / (float)(2 * N_SAMP - 1));
    if (i < N_SAMP)
        out[4096 + i] = (float)i * ((N_SAMP / SW_F) / (float)(N_SAMP - 1));
}

extern "C" void kernel_launch(void* const* d_in, const int* in_sizes, int n_in,
                              void* d_out, int out_size, void* d_ws, size_t ws_size,
                              hipStream_t stream) {
    const float* h = (const float*)d_in[0];
    float* out = (float*)d_out;
    float* ws  = (float*)d_ws;

    float*  Vc   = ws;
    float*  Uc   = ws + 4096;
    float*  lam  = ws + 16384;
    float*  wc   = ws + 49280;
    int*    ab   = (int*)(ws + 52352);
    float*  fidfF= ws + 65664;
    float2* fidf = (float2*)(ws + 65664);
    float*  part = ws + 73856;

    k_eig<<<8, EIG_T, 0, stream>>>(h, Vc, Uc, lam);
    k_mwc<<<24, 128, 0, stream>>>(Vc, Uc, wc, ab);
    k_fid<<<512, 256, 0, stream>>>(wc, ab, lam, fidfF, out);
    k_dft<<<256, 256, 0, stream>>>(fidf, part);
    k_dredax<<<32, 256, 0, stream>>>(part, out);
}

// Round 26
// 61.975 us; speedup vs baseline: 2.2308x; 1.0623x over previous
//
#include <hip/hip_runtime.h>
#include <math.h>

#define N_SAMP 4096
#define NS     7
#define DT_F   1e-5f
#define B0_F   80.0f
#define T2_F   1.0f
#define SW_F   1000.0f
#define TWO_PI 6.2831853071795864769f
#define EIG_T  640   // 10 waves: exactly max pairs/round (C(5,2)=10)

// ws layout (floats): Vc 0..3432 | Uc 4096..7099 | lam 16384..16512 |
//                     wc 49280..52352 | ab(int) 52352..55424 |
//                     fidf(float2) 65664..73856 | part 73856..204928 (16*8192)
// out (f32, 24576): ReFID [0,4096) | time [4096,8192) |
//                   Re shifted spec [8192,16384) | freq [16384,24576)

// Sector eigensolver, two-sided Jacobi, sparsity-aware 21-round colored sweep
// (one wave per rotation pair; 10 waves cover the max matching).
__global__ __launch_bounds__(EIG_T) void k_eig(const float* __restrict__ h,
                                               float* __restrict__ Vc,
                                               float* __restrict__ Uc,
                                               float* __restrict__ lam_out) {
    const int nsz_[8]   = {1, 7, 21, 35, 35, 21, 7, 1};
    const int nbase_[8] = {0, 1, 8, 29, 64, 99, 120, 127};
    const int cum2_[8]  = {0, 1, 50, 491, 1716, 2941, 3382, 3431};
    const int offsU_[8] = {0, 0, 7, 154, 889, 2114, 2849, 2996}; // s>=1
    const int s    = blockIdx.x;
    const int ns   = nsz_[s];
    const int base = nbase_[s];
    const int tid  = threadIdx.x;
    const int wave = tid >> 6;
    const int lane = tid & 63;

    __shared__ float As[36 * 37];
    __shared__ float Vs[36 * 37];
    __shared__ int   st[36];
    __shared__ int   stm1[36];
    __shared__ int   inv[128];
    __shared__ float hs[49];
    __shared__ int   ppt2[21 * 12];   // bit-pair-colored pair lists
    __shared__ int   cnt2[21];

    const int ksm1 = (s >= 1) ? nsz_[s - 1] : 0;

    if (tid < 49) hs[tid] = h[tid];
    if (tid < 21) cnt2[tid] = 0;
    if (tid == 0) {
        int cnt = 0;
        for (int r = 0; r < 128; ++r) if (__popc(r) == s) st[cnt++] = r;
    }
    if (tid == 1 && s >= 1) {
        int cnt = 0;
        for (int r = 0; r < 128; ++r) if (__popc(r) == s - 1) stm1[cnt++] = r;
    }
    if (tid < 128 && __popc(tid) == s) {
        int cnt = 0;
        for (int r = 0; r < 128; ++r) { if (r == tid) break; if (__popc(r) == s) ++cnt; }
        inv[tid] = cnt;
    }
    for (int t = tid; t < 36 * 37; t += EIG_T) { As[t] = 0.f; Vs[t] = 0.f; }
    __syncthreads();

    // build the 21 matchings: round rid(i<j) holds pairs (inv[r], inv[r^m])
    if (ns > 1) {
        const int off_[7] = {0, 6, 11, 15, 18, 20, 0};
        for (int r = tid; r < 128; r += EIG_T) {
            if (__popc(r) == s) {
                for (int i = 0; i < 6; ++i) {
                    if (!((r >> i) & 1)) continue;
                    for (int j = i + 1; j < 7; ++j) {
                        if ((r >> j) & 1) continue;
                        int rid = off_[i] + (j - i - 1);
                        int prt = r ^ ((1 << i) | (1 << j));
                        int slot = atomicAdd(&cnt2[rid], 1);
                        ppt2[rid * 12 + slot] = (inv[r] << 8) | inv[prt];
                    }
                }
            }
        }
    }

    // Build sector Hamiltonian from h
    for (int t = tid; t < ns * ns; t += EIG_T) {
        int i = t / ns, j = t % ns;
        int r = st[i], c = st[j];
        float val = 0.f;
        if (r == c) {
            float acc = 0.f;
            for (int a = 0; a < 7; ++a) {
                float za = ((r >> (6 - a)) & 1) ? -0.5f : 0.5f;
                acc += B0_F * hs[a * 7 + a] * za;
                for (int b = a + 1; b < 7; ++b) {
                    float zb = ((r >> (6 - b)) & 1) ? -0.5f : 0.5f;
                    acc += hs[a * 7 + b] * za * zb;
                }
            }
            val = TWO_PI * acc;
        } else {
            int x = r ^ c;
            if (__popc(x) == 2) {
                int u = 31 - __clz(x);
                int v = __ffs(x) - 1;
                if (((r >> u) & 1) != ((r >> v) & 1))
                    val = TWO_PI * 0.5f * hs[(6 - u) * 7 + (6 - v)];
            }
        }
        As[i * 37 + j] = val;
    }
    for (int i = tid; i < ns; i += EIG_T) Vs[i * 37 + i] = 1.f;
    __syncthreads();

    if (ns > 1) {
        for (int t = 0; t < 21; ++t) {
            int npr = cnt2[t];
            float c0 = 1.f, s0 = 0.f;
            int   pq0 = -1;
            // ---- phase R: A-rows + V-rows; (c,s) in-wave, registered
            if (wave < npr) {
                int pq = ppt2[t * 12 + wave];
                int p = pq >> 8, q = pq & 255;
                float app = As[p * 37 + p];
                float aqq = As[q * 37 + q];
                float apq = As[p * 37 + q];
                float c = 1.f, sn = 0.f;
                if (fabsf(apq) >= 1e-30f) {
                    float tau = (aqq - app) / (2.f * apq);
                    float tt  = copysignf(1.f / (fabsf(tau) + sqrtf(1.f + tau * tau)), tau);
                    c  = rsqrtf(1.f + tt * tt);
                    sn = tt * c;
                }
                c0 = c; s0 = sn; pq0 = pq;
                if (lane < ns) {
                    float ap = As[p * 37 + lane], aq = As[q * 37 + lane];
                    As[p * 37 + lane] = c * ap - sn * aq;
                    As[q * 37 + lane] = sn * ap + c * aq;
                    float vp = Vs[p * 37 + lane], vq = Vs[q * 37 + lane];
                    Vs[p * 37 + lane] = c * vp - sn * vq;
                    Vs[q * 37 + lane] = sn * vp + c * vq;
                }
            }
            __syncthreads();
            // ---- phase C: A-cols (registered (c,s))
            if (pq0 >= 0) {
                int p = pq0 >> 8, q = pq0 & 255;
                if (lane < ns) {
                    float ap = As[lane * 37 + p], aq = As[lane * 37 + q];
                    As[lane * 37 + p] = c0 * ap - s0 * aq;
                    As[lane * 37 + q] = s0 * ap + c0 * aq;
                }
            }
            __syncthreads();
        }
    }

    for (int i = tid; i < ns; i += EIG_T) lam_out[base + i] = As[i * 37 + i];
    // compact Vc writeback
    for (int t = tid; t < ns * ns; t += EIG_T) {
        int a = t / ns, k = t - (t / ns) * ns;
        Vc[cum2_[s] + t] = Vs[a * 37 + k];
    }
    // compact Uc writeback
    if (s >= 1) {
        for (int t = tid; t < ns * ksm1; t += EIG_T) {
            int a = t / ksm1, i = t - (t / ksm1) * ksm1;
            int rr = stm1[i];
            float uval = 0.f;
#pragma unroll
            for (int p = 0; p < 7; ++p)
                if (!((rr >> p) & 1)) uval += Vs[a * 37 + inv[rr + (1 << p)]];
            Uc[offsU_[s] + t] = uval;
        }
    }
}

// Compact W from compact Vc/Uc. 3003 entries padded to 3072.
__global__ __launch_bounds__(128) void k_mwc(const float* __restrict__ Vc,
                                             const float* __restrict__ Uc,
                                             float* __restrict__ wc,
                                             int* __restrict__ ab) {
    const int n1_[7]   = {1, 7, 21, 35, 35, 21, 7};
    const int n2_[7]   = {7, 21, 35, 35, 21, 7, 1};
    const int offs_[7] = {0, 7, 154, 889, 2114, 2849, 2996};
    const int nb1_[7]  = {0, 1, 8, 29, 64, 99, 120};
    const int nb2_[7]  = {1, 8, 29, 64, 99, 120, 127};
    const int cum2_[7] = {0, 1, 50, 491, 1716, 2941, 3382};
    int e = blockIdx.x * 128 + threadIdx.x;
    if (e >= 3072) return;
    if (e >= 3003) { wc[e] = 0.f; ab[e] = 0; return; }
    int t = 0;
#pragma unroll
    for (int u = 1; u < 7; ++u) if (e >= offs_[u]) t = u;
    int loc = e - offs_[t];
    int n1 = n1_[t], n2 = n2_[t];
    int i = loc / n2;
    int j = loc - i * n2;
    const float* va = &Vc[cum2_[t] + i * n1];
    const float* ub = &Uc[offs_[t] + j * n1];
    float acc = 0.f;
    for (int k = 0; k < n1; ++k) acc += va[k] * ub[k];
    wc[e] = 0.5f * acc * acc;
    ab[e] = ((nb1_[t] + i) << 7) | (nb2_[t] + j);
}

// 8 samples per block via phasor recurrence over the 3072 compact entries
__global__ __launch_bounds__(256) void k_fid(const float* __restrict__ wc,
                                             const int* __restrict__ ab,
                                             const float* __restrict__ lam,
                                             float* __restrict__ fidfF,
                                             float* __restrict__ out) {
    __shared__ float2 cb0[128], dd[128];
    __shared__ float  lred[4][16];
    const int n0  = blockIdx.x * 8;
    const int tid = threadIdx.x;
    const float t0 = (float)n0 * DT_F;
    if (tid < 128) {
        float sn, cs;
        sincosf(lam[tid] * t0, &sn, &cs);
        cb0[tid] = make_float2(cs, -sn);
        sincosf(lam[tid] * DT_F, &sn, &cs);
        dd[tid] = make_float2(cs, -sn);
    }
    __syncthreads();

    float ar0=0,ar1=0,ar2=0,ar3=0,ar4=0,ar5=0,ar6=0,ar7=0;
    float ai0=0,ai1=0,ai2=0,ai3=0,ai4=0,ai5=0,ai6=0,ai7=0;
#pragma unroll 4
    for (int i = 0; i < 12; ++i) {
        int e = i * 256 + tid;
        float w = wc[e];
        int pq = ab[e];
        int a = pq >> 7, b = pq & 127;
        float2 ca = cb0[a], cbv = cb0[b];
        float2 da = dd[a],  db  = dd[b];
        float zr = ca.x * cbv.x + ca.y * cbv.y;
        float zi = ca.x * cbv.y - ca.y * cbv.x;
        float fr = da.x * db.x + da.y * db.y;
        float fi = da.x * db.y - da.y * db.x;
        ar0 += w * zr; ai0 += w * zi; { float tr = zr*fr - zi*fi; zi = zr*fi + zi*fr; zr = tr; }
        ar1 += w * zr; ai1 += w * zi; { float tr = zr*fr - zi*fi; zi = zr*fi + zi*fr; zr = tr; }
        ar2 += w * zr; ai2 += w * zi; { float tr = zr*fr - zi*fi; zi = zr*fi + zi*fr; zr = tr; }
        ar3 += w * zr; ai3 += w * zi; { float tr = zr*fr - zi*fi; zi = zr*fi + zi*fr; zr = tr; }
        ar4 += w * zr; ai4 += w * zi; { float tr = zr*fr - zi*fi; zi = zr*fi + zi*fr; zr = tr; }
        ar5 += w * zr; ai5 += w * zi; { float tr = zr*fr - zi*fi; zi = zr*fi + zi*fr; zr = tr; }
        ar6 += w * zr; ai6 += w * zi; { float tr = zr*fr - zi*fi; zi = zr*fi + zi*fr; zr = tr; }
        ar7 += w * zr; ai7 += w * zi;
    }

    const int wave = tid >> 6, lane = tid & 63;
    float acc[16] = {ar0,ai0,ar1,ai1,ar2,ai2,ar3,ai3,ar4,ai4,ar5,ai5,ar6,ai6,ar7,ai7};
#pragma unroll 16
    for (int v = 0; v < 16; ++v) {
        float x = acc[v];
        for (int off = 32; off > 0; off >>= 1) x += __shfl_down(x, off);
        if (lane == 0) lred[wave][v] = x;
    }
    __syncthreads();
    if (tid < 16) {
        float x = lred[0][tid] + lred[1][tid] + lred[2][tid] + lred[3][tid];
        int jj = tid >> 1, c = tid & 1;
        int n = n0 + jj;
        float ap = expf(-(DT_F / T2_F) * (float)n);
        x *= ap;
        fidfF[2 * n + c] = x;
        if (c == 0) out[n] = x;
    }
}

// split-K shifted-spectrum partials: 16 chunks x 32 k-groups (512 blocks)
__global__ __launch_bounds__(256) void k_dft(const float2* __restrict__ fidf,
                                             float* __restrict__ part) {
    __shared__ float2 fs[256];
    const int tid = threadIdx.x;
    const int ch  = blockIdx.x >> 5;
    const int kb  = blockIdx.x & 31;
    const int n0  = ch * 256;
    fs[tid] = fidf[n0 + tid];
    __syncthreads();
    const int k = kb * 256 + tid;
    const int K = (k + 4096) & 8191;
    const float C = TWO_PI / 8192.0f;
    int idx = (n0 * K) & 8191;
    float ar = 0.f;
    for (int i = 0; i < 256; ++i) {
        float2 s = fs[i];
        float sn, cs;
        __sincosf(C * (float)idx, &sn, &cs);
        ar += s.x * cs + s.y * sn;
        idx = (idx + K) & 8191;
    }
    part[ch * 8192 + k] = ar;
}

// reduce partials + write axes
__global__ void k_dredax(const float* __restrict__ part, float* __restrict__ out) {
    int i = blockIdx.x * 256 + threadIdx.x;   // 0..8191
    float s = 0.f;
#pragma unroll
    for (int ch = 0; ch < 16; ++ch) s += part[ch * 8192 + i];
    out[8192 + i] = s;
    out[16384 + i] = -0.5f * SW_F + (float)i * (SW_F / (float)(2 * N_SAMP - 1));
    if (i < N_SAMP)
        out[4096 + i] = (float)i * ((N_SAMP / SW_F) / (float)(N_SAMP - 1));
}

extern "C" void kernel_launch(void* const* d_in, const int* in_sizes, int n_in,
                              void* d_out, int out_size, void* d_ws, size_t ws_size,
                              hipStream_t stream) {
    const float* h = (const float*)d_in[0];
    float* out = (float*)d_out;
    float* ws  = (float*)d_ws;

    float*  Vc   = ws;
    float*  Uc   = ws + 4096;
    float*  lam  = ws + 16384;
    float*  wc   = ws + 49280;
    int*    ab   = (int*)(ws + 52352);
    float*  fidfF= ws + 65664;
    float2* fidf = (float2*)(ws + 65664);
    float*  part = ws + 73856;

    k_eig<<<8, EIG_T, 0, stream>>>(h, Vc, Uc, lam);
    k_mwc<<<24, 128, 0, stream>>>(Vc, Uc, wc, ab);
    k_fid<<<512, 256, 0, stream>>>(wc, ab, lam, fidfF, out);
    k_dft<<<512, 256, 0, stream>>>(fidf, part);
    k_dredax<<<32, 256, 0, stream>>>(part, out);
}